// Round 5
// baseline (142.949 us; speedup 1.0000x reference)
//
#include <hip/hip_runtime.h>
#include <stdint.h>

// Problem constants
#define T_DIM 2048
#define B_DIM 32
#define DIN   512
#define DOUT  512
#define M_DIM (T_DIM * B_DIM)   // 65536
#define COLS  (B_DIM * DIN)     // 16384
#define COLS4 (COLS / 4)        // 4096

#define ALPHA_F 0.36787944117144233f  // exp(-1)
#define INV_1MA 1.5819767068693265f   // 1/(1-alpha)

#define HALO 8                        // alpha^8 ~ 3.4e-4 (tail -> ~1e-4 on out)

// Fallback-path chunking (round-1 fp32 path)
#define FCHUNKS  32
#define FCHUNK_T 64
#define FHALO    16

typedef float  floatx4 __attribute__((ext_vector_type(4)));
typedef __bf16 bf16x8  __attribute__((ext_vector_type(8)));

// pack two fp32 -> two bf16 (RNE) in one u32
__device__ __forceinline__ uint32_t pk2(float a, float b) {
  uint32_t ua = __float_as_uint(a); ua += 0x7fffu + ((ua >> 16) & 1u);
  uint32_t ub = __float_as_uint(b); ub += 0x7fffu + ((ub >> 16) & 1u);
  return (ua >> 16) | (ub & 0xffff0000u);
}

__device__ __forceinline__ void gload_lds16(const void* g, void* lds) {
  __builtin_amdgcn_global_load_lds(
      (const __attribute__((address_space(1))) void*)g,
      (__attribute__((address_space(3))) void*)lds,
      16, 0, 0);
}

// ---------------------------------------------------------------------------
// W fp32 -> bf16 (0.5 MB into ws). grid 16 x 256.
// ---------------------------------------------------------------------------
__global__ void wconv_kernel(const float* __restrict__ W,
                             uint16_t* __restrict__ WB)
{
  const int t = blockIdx.x * 256 + threadIdx.x;   // 0..4095
  const float4* W4 = (const float4*)W;
#pragma unroll
  for (int j = 0; j < 8; ++j) {
    const int b4 = t * 16 + j * 2;
    float4 w0 = W4[b4], w1 = W4[b4 + 1];
    uint4 p;
    p.x = pk2(w0.x, w0.y); p.y = pk2(w0.z, w0.w);
    p.z = pk2(w1.x, w1.y); p.w = pk2(w1.z, w1.w);
    *(uint4*)&WB[t * 64 + j * 8] = p;
  }
}

// ---------------------------------------------------------------------------
// FUSED kernel: filter(X) -> bf16 A-tile (registers->LDS) + MFMA GEMM + bias.
// BM=128 (4 t-steps), BN=128, BK=64; 256 thr / 4 waves (2x2), 64x64 per wave.
// A: per k-chunk, thread (b,oct) loads 12-t fp32 slab (8 halo + 4 main),
//    runs the alpha-chain, packs bf16, ds_write_b128 XOR-swizzled.
// B: pre-converted WB via global_load_lds w/ pre-swizzled source.
// Y[m,n] = xf[m,:]·W[n,:] + s(t)*bias[n],  s(t) = (1-alpha^(t+1))/(1-alpha)
// ---------------------------------------------------------------------------
__launch_bounds__(256, 2)
__global__ void fused_filter_gemm_kernel(const float* __restrict__ X,
                                         const uint16_t* __restrict__ WB,
                                         const float* __restrict__ bias,
                                         float* __restrict__ Y)
{
  __shared__ __align__(16) uint16_t As[128 * 64];
  __shared__ __align__(16) uint16_t Bs[128 * 64];

  // chunked XCD swizzle: 2048 blocks, 8 XCDs, 256 per XCD; n fastest within
  const int bid = blockIdx.x;
  const int lg = (bid & 7) * 256 + (bid >> 3);
  const int n0 = (lg & 3) * 128;
  const int m0 = (lg >> 2) * 128;
  const int t0 = m0 >> 5;            // first t of this tile (4 t-steps)

  const int tid  = threadIdx.x;
  const int lane = tid & 63;
  const int w    = tid >> 6;
  const int r    = lane & 15;
  const int q    = lane >> 4;
  const int wm   = w >> 1;
  const int wn   = w & 1;

  // A-staging mapping: thread -> (b, k-oct)
  const int b_   = tid >> 3;         // 0..31
  const int oct  = tid & 7;          // 0..7
  const int aslot = (oct ^ (b_ & 7)) << 3;   // swizzled ushort offset in row

  // B-staging geometry (global_load_lds): wave w, instr i -> rows w*32+i*8..+7
  const int srow_base = w * 32 + (lane >> 3);
  const int schunk    = lane & 7;

  const float4* X4 = (const float4*)X;

  floatx4 acc[4][4];
#pragma unroll
  for (int i = 0; i < 4; ++i)
#pragma unroll
    for (int j = 0; j < 4; ++j) {
      floatx4 z = {0.0f, 0.0f, 0.0f, 0.0f};
      acc[i][j] = z;
    }

  const float4 zero4 = {0.0f, 0.0f, 0.0f, 0.0f};

  for (int kt = 0; kt < DIN / 64; ++kt) {
    const int k4 = kt * 16;          // k0/4 in float4 units

    // ---- B tile: global_load_lds from WB, pre-swizzled source ----
#pragma unroll
    for (int i = 0; i < 4; ++i) {
      const int row = srow_base + i * 8;
      const int sc = schunk ^ (row & 7);
      gload_lds16(WB + (size_t)(n0 + row) * DIN + kt * 64 + sc * 8,
                  &Bs[(w * 32 + i * 8) * 64]);
    }

    // ---- A slab: 12 t-steps x (b, oct*8..+7) fp32, all loads up front ----
    float4 hx0[HALO], hx1[HALO];
#pragma unroll
    for (int j = 0; j < HALO; ++j) {
      const int t = t0 - HALO + j;
      if (t >= 0) {
        const size_t f4 = (size_t)(t * 32 + b_) * 128 + k4 + oct * 2;
        hx0[j] = X4[f4];
        hx1[j] = X4[f4 + 1];
      } else {
        hx0[j] = zero4; hx1[j] = zero4;
      }
    }
    float4 mx0[4], mx1[4];
#pragma unroll
    for (int j = 0; j < 4; ++j) {
      const size_t f4 = (size_t)((t0 + j) * 32 + b_) * 128 + k4 + oct * 2;
      mx0[j] = X4[f4];
      mx1[j] = X4[f4 + 1];
    }

    // ---- filter chain + pack + LDS write ----
    float4 c0 = zero4, c1 = zero4;
#pragma unroll
    for (int j = 0; j < HALO; ++j) {
      c0.x = fmaf(ALPHA_F, c0.x, hx0[j].x); c0.y = fmaf(ALPHA_F, c0.y, hx0[j].y);
      c0.z = fmaf(ALPHA_F, c0.z, hx0[j].z); c0.w = fmaf(ALPHA_F, c0.w, hx0[j].w);
      c1.x = fmaf(ALPHA_F, c1.x, hx1[j].x); c1.y = fmaf(ALPHA_F, c1.y, hx1[j].y);
      c1.z = fmaf(ALPHA_F, c1.z, hx1[j].z); c1.w = fmaf(ALPHA_F, c1.w, hx1[j].w);
    }
#pragma unroll
    for (int j = 0; j < 4; ++j) {
      c0.x = fmaf(ALPHA_F, c0.x, mx0[j].x); c0.y = fmaf(ALPHA_F, c0.y, mx0[j].y);
      c0.z = fmaf(ALPHA_F, c0.z, mx0[j].z); c0.w = fmaf(ALPHA_F, c0.w, mx0[j].w);
      c1.x = fmaf(ALPHA_F, c1.x, mx1[j].x); c1.y = fmaf(ALPHA_F, c1.y, mx1[j].y);
      c1.z = fmaf(ALPHA_F, c1.z, mx1[j].z); c1.w = fmaf(ALPHA_F, c1.w, mx1[j].w);
      uint4 p;
      p.x = pk2(c0.x, c0.y); p.y = pk2(c0.z, c0.w);
      p.z = pk2(c1.x, c1.y); p.w = pk2(c1.z, c1.w);
      *(uint4*)&As[(j * 32 + b_) * 64 + aslot] = p;
    }

    __syncthreads();   // drains vmcnt (B) + lgkmcnt (A writes)

    // ---- MFMA: 2 k-substeps of K=32, 16 mfma each ----
#pragma unroll
    for (int kk = 0; kk < 2; ++kk) {
      bf16x8 af[4], bfr[4];
#pragma unroll
      for (int mi = 0; mi < 4; ++mi) {
        const int row = wm * 64 + mi * 16 + r;
        const int cch = (kk * 4 + q) ^ (row & 7);
        af[mi] = *(const bf16x8*)&As[row * 64 + (cch << 3)];
      }
#pragma unroll
      for (int ni = 0; ni < 4; ++ni) {
        const int row = wn * 64 + ni * 16 + r;
        const int cch = (kk * 4 + q) ^ (row & 7);
        bfr[ni] = *(const bf16x8*)&Bs[row * 64 + (cch << 3)];
      }
#pragma unroll
      for (int mi = 0; mi < 4; ++mi)
#pragma unroll
        for (int ni = 0; ni < 4; ++ni)
          acc[mi][ni] = __builtin_amdgcn_mfma_f32_16x16x32_bf16(
              af[mi], bfr[ni], acc[mi][ni], 0, 0, 0);
    }
    __syncthreads();
  }

  // epilogue: + s(t)*bias
#pragma unroll
  for (int mi = 0; mi < 4; ++mi) {
    const int rowb = m0 + wm * 64 + mi * 16;   // 16-row granule, t uniform
    const int t = rowb >> 5;
    const float s = (1.0f - __expf(-(float)(t + 1))) * INV_1MA;
#pragma unroll
    for (int ni = 0; ni < 4; ++ni) {
      const int col = n0 + wn * 64 + ni * 16 + r;
      const float sb = s * bias[col];
#pragma unroll
      for (int j = 0; j < 4; ++j)
        Y[(size_t)(rowb + q * 4 + j) * DOUT + col] = acc[mi][ni][j] + sb;
    }
  }
}

// ===========================================================================
// FALLBACK PATH (fp32 GEMM + scan; used only if ws < 1 MB)
// ===========================================================================
__launch_bounds__(256, 2)
__global__ void gemm_bias_kernel(const float* __restrict__ X,
                                 const float* __restrict__ W,
                                 const float* __restrict__ bias,
                                 float* __restrict__ Y,
                                 float* __restrict__ halo,
                                 int halo_on)
{
  __shared__ __align__(16) uint16_t As[128 * 64];
  __shared__ __align__(16) uint16_t Bs[128 * 64];

  const int tid  = threadIdx.x;
  const int lane = tid & 63;
  const int wave = tid >> 6;
  const int wm   = wave >> 1;
  const int wn   = wave & 1;
  const int r    = lane & 15;
  const int q    = lane >> 4;

  const int m0 = blockIdx.y * 128;
  const int n0 = blockIdx.x * 128;

  floatx4 acc[4][4];
#pragma unroll
  for (int i = 0; i < 4; ++i)
#pragma unroll
    for (int j = 0; j < 4; ++j) {
      floatx4 z = {0.0f, 0.0f, 0.0f, 0.0f};
      acc[i][j] = z;
    }

  for (int kt = 0; kt < DIN / 64; ++kt) {
    const int k0 = kt * 64;
#pragma unroll
    for (int j = 0; j < 4; ++j) {
      const int cid = tid + j * 256;
      const int row = cid >> 3;
      const int c   = cid & 7;
      const int slot = (c ^ (row & 7)) << 3;

      const float* ga = &X[(size_t)(m0 + row) * DIN + k0 + c * 8];
      float4 a0 = *(const float4*)ga;
      float4 a1 = *(const float4*)(ga + 4);
      uint4 pa;
      pa.x = pk2(a0.x, a0.y); pa.y = pk2(a0.z, a0.w);
      pa.z = pk2(a1.x, a1.y); pa.w = pk2(a1.z, a1.w);
      *(uint4*)&As[row * 64 + slot] = pa;

      const float* gb = &W[(size_t)(n0 + row) * DIN + k0 + c * 8];
      float4 b0 = *(const float4*)gb;
      float4 b1 = *(const float4*)(gb + 4);
      uint4 pb;
      pb.x = pk2(b0.x, b0.y); pb.y = pk2(b0.z, b0.w);
      pb.z = pk2(b1.x, b1.y); pb.w = pk2(b1.z, b1.w);
      *(uint4*)&Bs[row * 64 + slot] = pb;
    }
    __syncthreads();

#pragma unroll
    for (int kk = 0; kk < 2; ++kk) {
      bf16x8 af[4], bfr[4];
#pragma unroll
      for (int mi = 0; mi < 4; ++mi) {
        const int row = wm * 64 + mi * 16 + r;
        const int c   = (kk * 4 + q) ^ (row & 7);
        af[mi] = *(const bf16x8*)&As[row * 64 + (c << 3)];
      }
#pragma unroll
      for (int ni = 0; ni < 4; ++ni) {
        const int row = wn * 64 + ni * 16 + r;
        const int c   = (kk * 4 + q) ^ (row & 7);
        bfr[ni] = *(const bf16x8*)&Bs[row * 64 + (c << 3)];
      }
#pragma unroll
      for (int mi = 0; mi < 4; ++mi)
#pragma unroll
        for (int ni = 0; ni < 4; ++ni)
          acc[mi][ni] = __builtin_amdgcn_mfma_f32_16x16x32_bf16(
              af[mi], bfr[ni], acc[mi][ni], 0, 0, 0);
    }
    __syncthreads();
  }

#pragma unroll
  for (int ni = 0; ni < 4; ++ni) {
    const int col = n0 + wn * 64 + ni * 16 + r;
    const float bv = bias[col];
#pragma unroll
    for (int mi = 0; mi < 4; ++mi) {
      const int rowm = m0 + wm * 64 + mi * 16 + q * 4;
      const int t = rowm >> 5;
      const int b = rowm & 31;
      const int tloc = t & (FCHUNK_T - 1);
      const bool hw = halo_on && (tloc >= FCHUNK_T - FHALO) && (t < T_DIM - FCHUNK_T);
      const size_t hbase = hw
          ? ((size_t)(((t >> 6) + 1) * FHALO + (tloc - (FCHUNK_T - FHALO))) * COLS)
          : 0;
#pragma unroll
      for (int j = 0; j < 4; ++j) {
        const float v = acc[mi][ni][j] + bv;
        Y[(size_t)(rowm + j) * DOUT + col] = v;
        if (hw) halo[hbase + (size_t)(b + j) * DOUT + col] = v;
      }
    }
  }
}

__global__ void scan_kernel(float* __restrict__ Y,
                            const float* __restrict__ halo,
                            int chunk_len)
{
  const int col4 = blockIdx.x * blockDim.x + threadIdx.x;
  const int c = blockIdx.y;

  float4* Y4 = (float4*)Y;
  const float4* H4 = (const float4*)halo;

  float4 carry = {0.0f, 0.0f, 0.0f, 0.0f};
  if (c > 0) {
#pragma unroll
    for (int h = 0; h < FHALO; ++h) {
      float4 v = H4[(size_t)(c * FHALO + h) * COLS4 + col4];
      carry.x = fmaf(ALPHA_F, carry.x, v.x);
      carry.y = fmaf(ALPHA_F, carry.y, v.y);
      carry.z = fmaf(ALPHA_F, carry.z, v.z);
      carry.w = fmaf(ALPHA_F, carry.w, v.w);
    }
  }

  size_t idx = (size_t)c * chunk_len * COLS4 + col4;
  float4 ynext = Y4[idx];
  for (int t = 0; t < chunk_len; ++t) {
    float4 y = ynext;
    if (t + 1 < chunk_len) ynext = Y4[idx + COLS4];
    carry.x = fmaf(ALPHA_F, carry.x, y.x);
    carry.y = fmaf(ALPHA_F, carry.y, y.y);
    carry.z = fmaf(ALPHA_F, carry.z, y.z);
    carry.w = fmaf(ALPHA_F, carry.w, y.w);
    Y4[idx] = carry;
    idx += COLS4;
  }
}

// ---------------------------------------------------------------------------
extern "C" void kernel_launch(void* const* d_in, const int* in_sizes, int n_in,
                              void* d_out, int out_size, void* d_ws, size_t ws_size,
                              hipStream_t stream)
{
  const float* X    = (const float*)d_in[0];  // [T, B, DIN]
  const float* W    = (const float*)d_in[1];  // [DOUT, DIN]
  const float* bias = (const float*)d_in[2];  // [DOUT]
  float* Y = (float*)d_out;                   // [T, B, DOUT]

  const size_t need_wb = (size_t)DOUT * DIN * 2;  // 512 KiB

  if (ws_size >= need_wb) {
    uint16_t* WB = (uint16_t*)d_ws;
    wconv_kernel<<<16, 256, 0, stream>>>(W, WB);
    fused_filter_gemm_kernel<<<2048, 256, 0, stream>>>(X, WB, bias, Y);
  } else {
    float* halo = (float*)d_ws;
    const size_t halo_need = (size_t)FCHUNKS * FHALO * COLS * sizeof(float);
    const int halo_on = (ws_size >= halo_need) ? 1 : 0;

    dim3 g1(DOUT / 128, M_DIM / 128);
    gemm_bias_kernel<<<g1, 256, 0, stream>>>(X, W, bias, Y, halo, halo_on);

    const int n_chunks = halo_on ? FCHUNKS : 1;
    dim3 g2(COLS4 / 256, n_chunks);
    scan_kernel<<<g2, 256, 0, stream>>>(Y, halo, T_DIM / n_chunks);
  }
}

// Round 6
// 107.574 us; speedup vs baseline: 1.3288x; 1.3288x over previous
//
#include <hip/hip_runtime.h>
#include <stdint.h>

// Problem constants
#define T_DIM 2048
#define B_DIM 32
#define DIN   512
#define DOUT  512
#define M_DIM (T_DIM * B_DIM)   // 65536
#define COLS  (B_DIM * DIN)     // 16384
#define COLS4 (COLS / 4)        // 4096

#define ALPHA_F 0.36787944117144233f  // exp(-1)
#define INV_1MA 1.5819767068693265f   // 1/(1-alpha)

// Filter chunking: 128 chunks of 16 timesteps, 8-step halo (alpha^8 ~ 3.4e-4
// on xf -> ~1e-4 on out after the 512-dot; far below bf16-GEMM floor 0.0156)
#define CHUNKS   128
#define CHUNK_T  16
#define HALO     8

// Fallback-path chunking (round-1 fp32 path)
#define FCHUNKS  32
#define FCHUNK_T 64
#define FHALO    16

typedef float  floatx4 __attribute__((ext_vector_type(4)));
typedef __bf16 bf16x8  __attribute__((ext_vector_type(8)));

// pack two fp32 -> two bf16 (RNE) in one u32
__device__ __forceinline__ uint32_t pk2(float a, float b) {
  uint32_t ua = __float_as_uint(a); ua += 0x7fffu + ((ua >> 16) & 1u);
  uint32_t ub = __float_as_uint(b); ub += 0x7fffu + ((ub >> 16) & 1u);
  return (ua >> 16) | (ub & 0xffff0000u);
}

__device__ __forceinline__ void gload_lds16(const void* g, void* lds) {
  __builtin_amdgcn_global_load_lds(
      (const __attribute__((address_space(1))) void*)g,
      (__attribute__((address_space(3))) void*)lds,
      16, 0, 0);
}

__device__ __forceinline__ void fma4(float4& c, const float4& v) {
  c.x = fmaf(ALPHA_F, c.x, v.x);
  c.y = fmaf(ALPHA_F, c.y, v.y);
  c.z = fmaf(ALPHA_F, c.z, v.z);
  c.w = fmaf(ALPHA_F, c.w, v.w);
}

// ---------------------------------------------------------------------------
// W fp32 -> bf16 (0.5 MB into ws). grid 16 x 256.
// ---------------------------------------------------------------------------
__global__ void wconv_kernel(const float* __restrict__ W,
                             uint16_t* __restrict__ WB)
{
  const int t = blockIdx.x * 256 + threadIdx.x;   // 0..4095
  const float4* W4 = (const float4*)W;
#pragma unroll
  for (int j = 0; j < 8; ++j) {
    const int b4 = t * 16 + j * 2;
    float4 w0 = W4[b4], w1 = W4[b4 + 1];
    uint4 p;
    p.x = pk2(w0.x, w0.y); p.y = pk2(w0.z, w0.w);
    p.z = pk2(w1.x, w1.y); p.w = pk2(w1.z, w1.w);
    *(uint4*)&WB[t * 64 + j * 8] = p;
  }
}

// ---------------------------------------------------------------------------
// Kernel 1: chunked exponential filter on X (fp32 -> bf16 XF).
// grid (8, CHUNKS) x 256. Thread owns 8 consecutive floats (2 float4).
// Halo: 16 upfront loads -> carry. Main: 4 groups of 4 t, depth-2 pipelined
// (group g+1's 8 loads issue before group g's fma/pack/store). 16B stores.
// ---------------------------------------------------------------------------
__global__ void filter_x_kernel(const float* __restrict__ X,
                                uint16_t* __restrict__ XF)
{
  const int col8 = blockIdx.x * 256 + threadIdx.x;  // 0..2047
  const int c = blockIdx.y;
  const float4* X4 = (const float4*)X;

  const size_t cbase = (size_t)c * CHUNK_T * COLS4 + col8 * 2;

  float4 ca = {0.0f, 0.0f, 0.0f, 0.0f};
  float4 cb = {0.0f, 0.0f, 0.0f, 0.0f};

  if (c > 0) {
    float4 h[2 * HALO];
    const size_t hb = cbase - (size_t)HALO * COLS4;
#pragma unroll
    for (int j = 0; j < HALO; ++j) {
      h[2 * j]     = X4[hb + (size_t)j * COLS4];
      h[2 * j + 1] = X4[hb + (size_t)j * COLS4 + 1];
    }
#pragma unroll
    for (int j = 0; j < HALO; ++j) {
      fma4(ca, h[2 * j]);
      fma4(cb, h[2 * j + 1]);
    }
  }

  // main: 16 t in 4 groups of 4, depth-2 pipeline
  float4 cur[8], nxt[8];
#pragma unroll
  for (int j = 0; j < 4; ++j) {
    cur[2 * j]     = X4[cbase + (size_t)j * COLS4];
    cur[2 * j + 1] = X4[cbase + (size_t)j * COLS4 + 1];
  }
#pragma unroll
  for (int g = 0; g < 4; ++g) {
    if (g < 3) {
      const size_t nb = cbase + (size_t)((g + 1) * 4) * COLS4;
#pragma unroll
      for (int j = 0; j < 4; ++j) {
        nxt[2 * j]     = X4[nb + (size_t)j * COLS4];
        nxt[2 * j + 1] = X4[nb + (size_t)j * COLS4 + 1];
      }
    }
#pragma unroll
    for (int j = 0; j < 4; ++j) {
      fma4(ca, cur[2 * j]);
      fma4(cb, cur[2 * j + 1]);
      uint4 p;
      p.x = pk2(ca.x, ca.y); p.y = pk2(ca.z, ca.w);
      p.z = pk2(cb.x, cb.y); p.w = pk2(cb.z, cb.w);
      *(uint4*)&XF[(cbase + (size_t)(g * 4 + j) * COLS4) * 4] = p;
    }
#pragma unroll
    for (int j = 0; j < 8; ++j) cur[j] = nxt[j];
  }
}

// ---------------------------------------------------------------------------
// Kernel 2: bf16 GEMM (m97 structure): Y[m,n] = XF[m,:]·WB[n,:] + s(t)·bias[n]
// BM=BN=128, BK=64; 256 thr / 4 waves (2x2), 64x64 per wave.
// global_load_lds width16 with PRE-SWIZZLED global source (linear LDS dest),
// XOR-swizzled ds_read_b128 (conflict-free), chunked XCD swizzle.
// ---------------------------------------------------------------------------
__launch_bounds__(256, 4)
__global__ void gemm_bf16_kernel(const uint16_t* __restrict__ XF,
                                 const uint16_t* __restrict__ WB,
                                 const float* __restrict__ bias,
                                 float* __restrict__ Y)
{
  __shared__ __align__(16) uint16_t As[128 * 64];
  __shared__ __align__(16) uint16_t Bs[128 * 64];

  const int bid = blockIdx.x;
  const int lg = (bid & 7) * 256 + (bid >> 3);
  const int n0 = (lg & 3) * 128;
  const int m0 = (lg >> 2) * 128;

  const int tid  = threadIdx.x;
  const int lane = tid & 63;
  const int w    = tid >> 6;
  const int r    = lane & 15;
  const int q    = lane >> 4;
  const int wm   = w >> 1;
  const int wn   = w & 1;

  const int srow_base = w * 32 + (lane >> 3);
  const int schunk    = lane & 7;

  floatx4 acc[4][4];
#pragma unroll
  for (int i = 0; i < 4; ++i)
#pragma unroll
    for (int j = 0; j < 4; ++j) {
      floatx4 z = {0.0f, 0.0f, 0.0f, 0.0f};
      acc[i][j] = z;
    }

  for (int kt = 0; kt < DIN / 64; ++kt) {
    const int k0 = kt * 64;
#pragma unroll
    for (int i = 0; i < 4; ++i) {
      const int row = srow_base + i * 8;
      const int sc = schunk ^ (row & 7);
      gload_lds16(XF + (size_t)(m0 + row) * DIN + k0 + sc * 8,
                  &As[(w * 32 + i * 8) * 64]);
      gload_lds16(WB + (size_t)(n0 + row) * DIN + k0 + sc * 8,
                  &Bs[(w * 32 + i * 8) * 64]);
    }
    __syncthreads();

#pragma unroll
    for (int kk = 0; kk < 2; ++kk) {
      bf16x8 af[4], bfr[4];
#pragma unroll
      for (int mi = 0; mi < 4; ++mi) {
        const int row = wm * 64 + mi * 16 + r;
        const int cch = (kk * 4 + q) ^ (row & 7);
        af[mi] = *(const bf16x8*)&As[row * 64 + (cch << 3)];
      }
#pragma unroll
      for (int ni = 0; ni < 4; ++ni) {
        const int row = wn * 64 + ni * 16 + r;
        const int cch = (kk * 4 + q) ^ (row & 7);
        bfr[ni] = *(const bf16x8*)&Bs[row * 64 + (cch << 3)];
      }
#pragma unroll
      for (int mi = 0; mi < 4; ++mi)
#pragma unroll
        for (int ni = 0; ni < 4; ++ni)
          acc[mi][ni] = __builtin_amdgcn_mfma_f32_16x16x32_bf16(
              af[mi], bfr[ni], acc[mi][ni], 0, 0, 0);
    }
    __syncthreads();
  }

#pragma unroll
  for (int mi = 0; mi < 4; ++mi) {
    const int rowb = m0 + wm * 64 + mi * 16;
    const int t = rowb >> 5;
    const float s = (1.0f - __expf(-(float)(t + 1))) * INV_1MA;
#pragma unroll
    for (int ni = 0; ni < 4; ++ni) {
      const int col = n0 + wn * 64 + ni * 16 + r;
      const float sb = s * bias[col];
#pragma unroll
      for (int j = 0; j < 4; ++j)
        Y[(size_t)(rowb + q * 4 + j) * DOUT + col] = acc[mi][ni][j] + sb;
    }
  }
}

// ===========================================================================
// FALLBACK PATH (fp32 GEMM + scan; used only if ws < 1 MB)
// ===========================================================================
__launch_bounds__(256, 2)
__global__ void gemm_bias_kernel(const float* __restrict__ X,
                                 const float* __restrict__ W,
                                 const float* __restrict__ bias,
                                 float* __restrict__ Y,
                                 float* __restrict__ halo,
                                 int halo_on)
{
  __shared__ __align__(16) uint16_t As[128 * 64];
  __shared__ __align__(16) uint16_t Bs[128 * 64];

  const int tid  = threadIdx.x;
  const int lane = tid & 63;
  const int wave = tid >> 6;
  const int wm   = wave >> 1;
  const int wn   = wave & 1;
  const int r    = lane & 15;
  const int q    = lane >> 4;

  const int m0 = blockIdx.y * 128;
  const int n0 = blockIdx.x * 128;

  floatx4 acc[4][4];
#pragma unroll
  for (int i = 0; i < 4; ++i)
#pragma unroll
    for (int j = 0; j < 4; ++j) {
      floatx4 z = {0.0f, 0.0f, 0.0f, 0.0f};
      acc[i][j] = z;
    }

  for (int kt = 0; kt < DIN / 64; ++kt) {
    const int k0 = kt * 64;
#pragma unroll
    for (int j = 0; j < 4; ++j) {
      const int cid = tid + j * 256;
      const int row = cid >> 3;
      const int c   = cid & 7;
      const int slot = (c ^ (row & 7)) << 3;

      const float* ga = &X[(size_t)(m0 + row) * DIN + k0 + c * 8];
      float4 a0 = *(const float4*)ga;
      float4 a1 = *(const float4*)(ga + 4);
      uint4 pa;
      pa.x = pk2(a0.x, a0.y); pa.y = pk2(a0.z, a0.w);
      pa.z = pk2(a1.x, a1.y); pa.w = pk2(a1.z, a1.w);
      *(uint4*)&As[row * 64 + slot] = pa;

      const float* gb = &W[(size_t)(n0 + row) * DIN + k0 + c * 8];
      float4 b0 = *(const float4*)gb;
      float4 b1 = *(const float4*)(gb + 4);
      uint4 pb;
      pb.x = pk2(b0.x, b0.y); pb.y = pk2(b0.z, b0.w);
      pb.z = pk2(b1.x, b1.y); pb.w = pk2(b1.z, b1.w);
      *(uint4*)&Bs[row * 64 + slot] = pb;
    }
    __syncthreads();

#pragma unroll
    for (int kk = 0; kk < 2; ++kk) {
      bf16x8 af[4], bfr[4];
#pragma unroll
      for (int mi = 0; mi < 4; ++mi) {
        const int row = wm * 64 + mi * 16 + r;
        const int c   = (kk * 4 + q) ^ (row & 7);
        af[mi] = *(const bf16x8*)&As[row * 64 + (c << 3)];
      }
#pragma unroll
      for (int ni = 0; ni < 4; ++ni) {
        const int row = wn * 64 + ni * 16 + r;
        const int c   = (kk * 4 + q) ^ (row & 7);
        bfr[ni] = *(const bf16x8*)&Bs[row * 64 + (c << 3)];
      }
#pragma unroll
      for (int mi = 0; mi < 4; ++mi)
#pragma unroll
        for (int ni = 0; ni < 4; ++ni)
          acc[mi][ni] = __builtin_amdgcn_mfma_f32_16x16x32_bf16(
              af[mi], bfr[ni], acc[mi][ni], 0, 0, 0);
    }
    __syncthreads();
  }

#pragma unroll
  for (int ni = 0; ni < 4; ++ni) {
    const int col = n0 + wn * 64 + ni * 16 + r;
    const float bv = bias[col];
#pragma unroll
    for (int mi = 0; mi < 4; ++mi) {
      const int rowm = m0 + wm * 64 + mi * 16 + q * 4;
      const int t = rowm >> 5;
      const int b = rowm & 31;
      const int tloc = t & (FCHUNK_T - 1);
      const bool hw = halo_on && (tloc >= FCHUNK_T - FHALO) && (t < T_DIM - FCHUNK_T);
      const size_t hbase = hw
          ? ((size_t)(((t >> 6) + 1) * FHALO + (tloc - (FCHUNK_T - FHALO))) * COLS)
          : 0;
#pragma unroll
      for (int j = 0; j < 4; ++j) {
        const float v = acc[mi][ni][j] + bv;
        Y[(size_t)(rowm + j) * DOUT + col] = v;
        if (hw) halo[hbase + (size_t)(b + j) * DOUT + col] = v;
      }
    }
  }
}

__global__ void scan_kernel(float* __restrict__ Y,
                            const float* __restrict__ halo,
                            int chunk_len)
{
  const int col4 = blockIdx.x * blockDim.x + threadIdx.x;
  const int c = blockIdx.y;

  float4* Y4 = (float4*)Y;
  const float4* H4 = (const float4*)halo;

  float4 carry = {0.0f, 0.0f, 0.0f, 0.0f};
  if (c > 0) {
#pragma unroll
    for (int h = 0; h < FHALO; ++h) {
      float4 v = H4[(size_t)(c * FHALO + h) * COLS4 + col4];
      fma4(carry, v);
    }
  }

  size_t idx = (size_t)c * chunk_len * COLS4 + col4;
  float4 ynext = Y4[idx];
  for (int t = 0; t < chunk_len; ++t) {
    float4 y = ynext;
    if (t + 1 < chunk_len) ynext = Y4[idx + COLS4];
    fma4(carry, y);
    Y4[idx] = carry;
    idx += COLS4;
  }
}

// ---------------------------------------------------------------------------
extern "C" void kernel_launch(void* const* d_in, const int* in_sizes, int n_in,
                              void* d_out, int out_size, void* d_ws, size_t ws_size,
                              hipStream_t stream)
{
  const float* X    = (const float*)d_in[0];  // [T, B, DIN]
  const float* W    = (const float*)d_in[1];  // [DOUT, DIN]
  const float* bias = (const float*)d_in[2];  // [DOUT]
  float* Y = (float*)d_out;                   // [T, B, DOUT]

  const size_t need_new = (size_t)M_DIM * DIN * 2 + (size_t)DOUT * DIN * 2; // 64.5 MiB

  if (ws_size >= need_new) {
    uint16_t* XF = (uint16_t*)d_ws;
    uint16_t* WB = XF + (size_t)M_DIM * DIN;

    wconv_kernel<<<16, 256, 0, stream>>>(W, WB);
    dim3 gf(8, CHUNKS);
    filter_x_kernel<<<gf, 256, 0, stream>>>(X, XF);
    gemm_bf16_kernel<<<2048, 256, 0, stream>>>(XF, WB, bias, Y);
  } else {
    float* halo = (float*)d_ws;
    const size_t halo_need = (size_t)FCHUNKS * FHALO * COLS * sizeof(float);
    const int halo_on = (ws_size >= halo_need) ? 1 : 0;

    dim3 g1(DOUT / 128, M_DIM / 128);
    gemm_bias_kernel<<<g1, 256, 0, stream>>>(X, W, bias, Y, halo, halo_on);

    const int n_chunks = halo_on ? FCHUNKS : 1;
    dim3 g2(COLS4 / 256, n_chunks);
    scan_kernel<<<g2, 256, 0, stream>>>(Y, halo, T_DIM / n_chunks);
  }
}